// Round 14
// baseline (354.517 us; speedup 1.0000x reference)
//
#include <hip/hip_runtime.h>
#include <hip/hip_bf16.h>
#include <math.h>

#define N 8192
#define D 128
#define MARGIN_V 0.3f
#define NEG_FILL 1000000.0f
#define GRID 512

typedef short bf16x8 __attribute__((ext_vector_type(8)));
typedef float f32x4  __attribute__((ext_vector_type(4)));

// Fragment-major layout of Fb: frag (g,q) holds rows 16g..16g+15, k 32q..32q+31,
// stored as 64 lanes x 16B: lane L = row (L&15), k-subchunk (L>>4)*8..+7.
// Short index: ((g*4 + q)*64 + L)*8 + j. Serves both A and B operands.
// cmeta[j] = { sq[j], bitcast(lab[j]) }. All per-block writes in phase 0 are
// whole-128B-line granular (Fb: 4KB contiguous; cmeta: 128B) -> XCD-L2 safe
// with device-scope release/acquire fences around the counter barrier.

__global__ __launch_bounds__(256) void fused_kernel(const float* __restrict__ F,
                                                    const int* __restrict__ lab,
                                                    unsigned short* __restrict__ Fb,
                                                    float2* __restrict__ cmeta,
                                                    unsigned* __restrict__ ap,
                                                    unsigned* __restrict__ an,
                                                    unsigned* __restrict__ ctr,
                                                    float* __restrict__ out) {
    __shared__ float red[16][17];
    __shared__ float s4[4];
    const int tid = threadIdx.x;
    const int bx  = blockIdx.x;

    // ================= phase 0: convert (one 16-row group per block) =========
    {
        const int g = bx;                     // 512 groups == GRID
        const int q = tid >> 6, L = tid & 63;
        const int m = L & 15, j8 = (L >> 4) * 8;

        const float* src = F + (size_t)(16 * g + m) * D + 32 * q + j8;
        float4 v0 = *(const float4*)src;
        float4 v1 = *(const float4*)(src + 4);

        float s = v0.x * v0.x + v0.y * v0.y + v0.z * v0.z + v0.w * v0.w
                + v1.x * v1.x + v1.y * v1.y + v1.z * v1.z + v1.w * v1.w;

        union { bf16x8 v; __hip_bfloat162 h2[4]; } pk;
        pk.h2[0] = __float22bfloat162_rn({v0.x, v0.y});
        pk.h2[1] = __float22bfloat162_rn({v0.z, v0.w});
        pk.h2[2] = __float22bfloat162_rn({v1.x, v1.y});
        pk.h2[3] = __float22bfloat162_rn({v1.z, v1.w});
        *(bf16x8*)&Fb[(size_t)g * 2048 + tid * 8] = pk.v;

        red[m][q * 4 + (L >> 4)] = s;
        __syncthreads();
        if (tid < 16) {
            float t = 0.f;
            #pragma unroll
            for (int c = 0; c < 16; ++c) t += red[tid][c];
            int row = 16 * g + tid;
            cmeta[row] = {t, __int_as_float(lab[row])};
        }
        int gid = bx * 256 + tid;
        if (gid < N) { ap[gid] = 0u; an[gid] = 0x7F800000u; }
    }

    // ================= barrier 1 (all GRID blocks co-resident) ===============
    __threadfence();            // release: drain + L2 writeback
    __syncthreads();
    if (tid == 0) {
        atomicAdd(ctr, 1u);
        while (atomicAdd(ctr, 0u) < GRID) { __builtin_amdgcn_s_sleep(2); }
    }
    __syncthreads();
    __threadfence();            // acquire: invalidate stale lines

    // ================= phase 1: gemm (zero-LDS, double-buffered B) ===========
    {
        const int wave = tid >> 6, lane = tid & 63;
        const int quad = lane >> 4, lr = lane & 15;
        const int s  = bx >> 3;                 // 64 strips of 128 rows
        const int cy = bx & 7;                  // 8 chunks of 1024 cols
        const int R0   = s * 128 + wave * 32;   // this wave's 32 rows
        const int g0   = R0 >> 4;
        const int cg0  = cy * 64;               // 64 col-groups in chunk
        const int colb = cy * 1024;

        bf16x8 af[2][4];
        #pragma unroll
        for (int a = 0; a < 2; ++a)
            #pragma unroll
            for (int ks = 0; ks < 4; ++ks)
                af[a][ks] = *(const bf16x8*)&Fb[(((size_t)(g0 + a) * 4 + ks) * 64 + lane) * 8];

        float sqi[2][4]; int labi[2][4];
        #pragma unroll
        for (int a = 0; a < 2; ++a)
            #pragma unroll
            for (int r = 0; r < 4; ++r) {
                float2 mt = cmeta[R0 + a * 16 + quad * 4 + r];
                sqi[a][r] = mt.x; labi[a][r] = __float_as_int(mt.y);
            }

        float rowP[2][4], rowN[2][4];
        #pragma unroll
        for (int a = 0; a < 2; ++a)
            #pragma unroll
            for (int r = 0; r < 4; ++r) { rowP[a][r] = -INFINITY; rowN[a][r] = INFINITY; }

        bf16x8 bf[2][2][4];          // [buf][b][ks]
        float  sqj[2][2];
        int    labj[2][2];

        // load tile 0 into buf 0
        #pragma unroll
        for (int b = 0; b < 2; ++b) {
            int gb = cg0 + b;
            #pragma unroll
            for (int ks = 0; ks < 4; ++ks)
                bf[0][b][ks] = *(const bf16x8*)&Fb[(((size_t)gb * 4 + ks) * 64 + lane) * 8];
            float2 mt = cmeta[colb + b * 16 + lr];
            sqj[0][b] = mt.x; labj[0][b] = __float_as_int(mt.y);
        }

        #pragma unroll 1
        for (int t = 0; t < 32; ++t) {
            const int cur = t & 1, nxt = cur ^ 1;
            // issue next tile's loads FIRST (independent buffer -> full-tile cover)
            if (t < 31) {
                #pragma unroll
                for (int b = 0; b < 2; ++b) {
                    int gb = cg0 + 2 * (t + 1) + b;
                    #pragma unroll
                    for (int ks = 0; ks < 4; ++ks)
                        bf[nxt][b][ks] = *(const bf16x8*)&Fb[(((size_t)gb * 4 + ks) * 64 + lane) * 8];
                    float2 mt = cmeta[colb + (t + 1) * 32 + b * 16 + lr];
                    sqj[nxt][b] = mt.x; labj[nxt][b] = __float_as_int(mt.y);
                }
            }
            // MFMA on current buffer
            f32x4 acc[2][2];
            #pragma unroll
            for (int a = 0; a < 2; ++a)
                #pragma unroll
                for (int b = 0; b < 2; ++b) acc[a][b] = {0.f, 0.f, 0.f, 0.f};
            #pragma unroll
            for (int ks = 0; ks < 4; ++ks)
                #pragma unroll
                for (int a = 0; a < 2; ++a)
                    #pragma unroll
                    for (int b = 0; b < 2; ++b)
                        acc[a][b] = __builtin_amdgcn_mfma_f32_16x16x32_bf16(
                            af[a][ks], bf[cur][b][ks], acc[a][b], 0, 0, 0);
            // mining epilogue (u = sqj - 2c domain)
            #pragma unroll
            for (int a = 0; a < 2; ++a)
                #pragma unroll
                for (int b = 0; b < 2; ++b)
                    #pragma unroll
                    for (int r = 0; r < 4; ++r) {
                        float u = fmaf(acc[a][b][r], -2.0f, sqj[cur][b]);
                        bool same = (labi[a][r] == labj[cur][b]);
                        rowP[a][r] = fmaxf(rowP[a][r], same ? u : -INFINITY);
                        rowN[a][r] = fminf(rowN[a][r], same ? INFINITY : u);
                    }
        }

        // reduce over 16 lr lanes, add sqi, clamp, atomic d^2-bit combine
        #pragma unroll
        for (int a = 0; a < 2; ++a)
            #pragma unroll
            for (int r = 0; r < 4; ++r) {
                float p = rowP[a][r], n = rowN[a][r];
                #pragma unroll
                for (int off = 1; off < 16; off <<= 1) {
                    p = fmaxf(p, __shfl_xor(p, off));
                    n = fminf(n, __shfl_xor(n, off));
                }
                rowP[a][r] = p; rowN[a][r] = n;
            }
        if (lr == 0) {
            #pragma unroll
            for (int a = 0; a < 2; ++a)
                #pragma unroll
                for (int r = 0; r < 4; ++r) {
                    int row = R0 + a * 16 + quad * 4 + r;
                    float pd2 = fmaxf(sqi[a][r] + rowP[a][r], 0.f);
                    float nd2 = fmaxf(sqi[a][r] + rowN[a][r], 0.f);
                    atomicMax(&ap[row], __float_as_uint(pd2));
                    atomicMin(&an[row], __float_as_uint(nd2));
                }
        }
    }

    // ================= barrier 2 + fused loss (block 0 only) =================
    __threadfence();
    __syncthreads();
    if (tid == 0) atomicAdd(ctr, 1u);
    if (bx != 0) return;
    if (tid == 0) { while (atomicAdd(ctr, 0u) < 2 * GRID) { __builtin_amdgcn_s_sleep(2); } }
    __syncthreads();
    __threadfence();

    {
        float sum = 0.f;
        #pragma unroll
        for (int k = 0; k < 8; ++k) {
            int i = k * 1024 + tid * 4;
            f32x4 a4 = *(const f32x4*)&((const float*)ap)[i];
            f32x4 n4 = *(const f32x4*)&((const float*)an)[i];
            #pragma unroll
            for (int c = 0; c < 4; ++c) {
                float apd = __builtin_amdgcn_sqrtf(a4[c]);
                float anv = n4[c];
                float and_ = (anv < INFINITY) ? __builtin_amdgcn_sqrtf(anv) : NEG_FILL;
                sum += fmaxf(0.f, MARGIN_V - (and_ - apd));
            }
        }
        #pragma unroll
        for (int off = 32; off >= 1; off >>= 1) sum += __shfl_xor(sum, off);
        if ((tid & 63) == 0) s4[tid >> 6] = sum;
        __syncthreads();
        if (tid == 0) out[0] = (s4[0] + s4[1] + s4[2] + s4[3]) * (1.0f / (float)N);
    }
}

extern "C" void kernel_launch(void* const* d_in, const int* in_sizes, int n_in,
                              void* d_out, int out_size, void* d_ws, size_t ws_size,
                              hipStream_t stream) {
    const float* F   = (const float*)d_in[0];
    const int*   lab = (const int*)d_in[1];

    unsigned short* Fb    = (unsigned short*)d_ws;           // 2 MB, frag-major
    float2*         cmeta = (float2*)(Fb + (size_t)N * D);   // 64 KB
    unsigned*       ap    = (unsigned*)(cmeta + N);          // 32 KB
    unsigned*       an    = ap + N;                          // 32 KB
    unsigned*       ctr   = an + N;                          // 4 B

    hipMemsetAsync(ctr, 0, sizeof(unsigned), stream);
    fused_kernel<<<GRID, 256, 0, stream>>>(F, lab, Fb, cmeta, ap, an, ctr, (float*)d_out);
}